// Round 1
// baseline (39.183 us; speedup 1.0000x reference)
//
#include <hip/hip_runtime.h>
#include <math.h>

// Fused DETR HungarianMatcher cost matrix:
//   C[nq, t] = 5*L1(pred_cxcywh, tgt_cxcywh) + 2*focal_class(prob[nq, label[t]])
//              - 2*GIoU(pred_xyxy, tgt_xyxy)
// NQ = 16*900 = 14400, T = 1600, C = 80. Output f32 [NQ, T] (= [16,900,1600]).

#define FALPHA  0.25f
#define W_CLASS 2.0f
#define W_BBOX  5.0f
#define W_GIOU  2.0f
#define FEPS    1e-8f

#define NCLS  80
#define QTILE 8
#define NTHR  256

__global__ __launch_bounds__(NTHR, 4)
void matcher_cost_kernel(const float* __restrict__ logits,   // [NQ, 80]
                         const float* __restrict__ pboxes,   // [NQ, 4] cxcywh
                         const float* __restrict__ tboxes,   // [T, 4] xyxy
                         const int*   __restrict__ tlabels,  // [T]
                         float* __restrict__ out,            // [NQ, T]
                         int NQ, int T)
{
    __shared__ float ccost[QTILE][NCLS];   // focal class cost per (query, class)
    __shared__ float qdat[QTILE][9];       // cx,cy,w,h, x1,y1,x2,y2, area

    const int tid = threadIdx.x;
    const int q0  = blockIdx.x * QTILE;

    // --- focal class-cost table for this block's 8 queries (640 entries) ---
    for (int i = tid; i < QTILE * NCLS; i += NTHR) {
        int q = i / NCLS, c = i - q * NCLS;
        int gq = q0 + q;
        float v = 0.0f;
        if (gq < NQ) {
            float x = logits[(size_t)gq * NCLS + c];
            float p = 1.0f / (1.0f + expf(-x));
            float pos = FALPHA * (1.0f - p) * (1.0f - p) * (-logf(p + FEPS));
            float neg = (1.0f - FALPHA) * p * p * (-logf(1.0f - p + FEPS));
            v = pos - neg;
        }
        ccost[q][c] = v;
    }

    // --- per-query box data (8 threads) ---
    if (tid < QTILE) {
        int gq = q0 + tid;
        float4 b = make_float4(0.f, 0.f, 0.f, 0.f);
        if (gq < NQ) b = reinterpret_cast<const float4*>(pboxes)[gq];
        float x1 = b.x - 0.5f * b.z, y1 = b.y - 0.5f * b.w;
        float x2 = b.x + 0.5f * b.z, y2 = b.y + 0.5f * b.w;
        qdat[tid][0] = b.x; qdat[tid][1] = b.y; qdat[tid][2] = b.z; qdat[tid][3] = b.w;
        qdat[tid][4] = x1;  qdat[tid][5] = y1;  qdat[tid][6] = x2;  qdat[tid][7] = y2;
        qdat[tid][8] = (x2 - x1) * (y2 - y1);   // match ref: area from converted xyxy
    }
    __syncthreads();

    // broadcast query data into registers (wave-uniform LDS reads, conflict-free)
    float qcx[QTILE], qcy[QTILE], qw[QTILE], qh[QTILE];
    float qx1[QTILE], qy1[QTILE], qx2[QTILE], qy2[QTILE], qa[QTILE];
#pragma unroll
    for (int q = 0; q < QTILE; ++q) {
        qcx[q] = qdat[q][0]; qcy[q] = qdat[q][1]; qw[q]  = qdat[q][2]; qh[q]  = qdat[q][3];
        qx1[q] = qdat[q][4]; qy1[q] = qdat[q][5]; qx2[q] = qdat[q][6]; qy2[q] = qdat[q][7];
        qa[q]  = qdat[q][8];
    }

    const bool full = (q0 + QTILE <= NQ);

    // lanes walk t (contiguous): coalesced tgt loads + coalesced stores
    for (int t = tid; t < T; t += NTHR) {
        float4 b = reinterpret_cast<const float4*>(tboxes)[t];  // xyxy
        int lab = tlabels[t];
        float bx1 = b.x, by1 = b.y, bx2 = b.z, by2 = b.w;
        float bcx = (bx1 + bx2) * 0.5f, bcy = (by1 + by2) * 0.5f;
        float bw  = bx2 - bx1,          bh  = by2 - by1;
        float ba  = bw * bh;

#pragma unroll
        for (int q = 0; q < QTILE; ++q) {
            float cls = ccost[q][lab];
            float l1 = fabsf(qcx[q] - bcx) + fabsf(qcy[q] - bcy)
                     + fabsf(qw[q]  - bw ) + fabsf(qh[q]  - bh );

            float ltx = fmaxf(qx1[q], bx1), lty = fmaxf(qy1[q], by1);
            float rbx = fminf(qx2[q], bx2), rby = fminf(qy2[q], by2);
            float iw = fmaxf(rbx - ltx, 0.0f), ih = fmaxf(rby - lty, 0.0f);
            float inter = iw * ih;
            float uni = qa[q] + ba - inter;

            float cltx = fminf(qx1[q], bx1), clty = fminf(qy1[q], by1);
            float crbx = fmaxf(qx2[q], bx2), crby = fmaxf(qy2[q], by2);
            float cw = fmaxf(crbx - cltx, 0.0f), ch = fmaxf(crby - clty, 0.0f);
            float ca = cw * ch;

            // v_rcp_f32 is ~1 ulp; error ~1e-7 vs 0.4 threshold
            float iou  = inter * __builtin_amdgcn_rcpf(uni);
            float giou = iou - (ca - uni) * __builtin_amdgcn_rcpf(ca);

            float cost = W_BBOX * l1 + W_CLASS * cls - W_GIOU * giou;
            if (full || (q0 + q < NQ))
                out[(size_t)(q0 + q) * T + t] = cost;
        }
    }
}

extern "C" void kernel_launch(void* const* d_in, const int* in_sizes, int n_in,
                              void* d_out, int out_size, void* d_ws, size_t ws_size,
                              hipStream_t stream) {
    const float* logits  = (const float*)d_in[0];  // [16,900,80]
    const float* pboxes  = (const float*)d_in[1];  // [16,900,4]
    const float* tboxes  = (const float*)d_in[2];  // [1600,4]
    const int*   tlabels = (const int*)d_in[3];    // [1600]
    float* out = (float*)d_out;

    const int NQ = in_sizes[1] / 4;   // 14400
    const int T  = in_sizes[2] / 4;   // 1600

    const int nblocks = (NQ + QTILE - 1) / QTILE;  // 1800
    matcher_cost_kernel<<<nblocks, NTHR, 0, stream>>>(logits, pboxes, tboxes,
                                                      tlabels, out, NQ, T);
}

// Round 2
// 38.102 us; speedup vs baseline: 1.0284x; 1.0284x over previous
//
#include <hip/hip_runtime.h>
#include <math.h>

// Fused DETR HungarianMatcher cost matrix:
//   C[nq, t] = 5*L1(pred_cxcywh, tgt_cxcywh) + 2*focal_cls(prob[nq, lab[t]])
//              - 2*GIoU(pred_xyxy, tgt_xyxy)
// NQ = 14400, T = 1600, C = 80. Output f32 [NQ, T].
//
// Layout: block = 256 thr, QTILE=4 queries/block (grid 3600). Lane owns a
// quad of 4 consecutive t -> float4 stores. Class table transposed
// ccT[label][q] so one ds_read_b128 gathers all 4 q values per t.
// W_CLASS and the GIoU "+2" constant are folded into the table.
// NOTE: no launch_bounds min-wave cap — round-1's (256,4) capped VGPR at 128
// and (theory) spilled the hoisted query state to scratch.

#define NCLS  80
#define QTILE 4
#define NTHR  256

__global__ __launch_bounds__(NTHR)
void matcher_cost_kernel(const float* __restrict__ logits,   // [NQ, 80]
                         const float* __restrict__ pboxes,   // [NQ, 4] cxcywh
                         const float* __restrict__ tboxes,   // [T, 4] xyxy
                         const int*   __restrict__ tlabels,  // [T]
                         float* __restrict__ out,            // [NQ, T]
                         int NQ, int T)
{
    __shared__ float ccT[NCLS][QTILE];   // [label][q] : 2*cls + 2

    const int tid = threadIdx.x;
    const int q0  = blockIdx.x * QTILE;

    // --- focal class-cost table, transposed (320 entries) ---
    for (int i = tid; i < NCLS * QTILE; i += NTHR) {
        int q = i / NCLS, lab = i - q * NCLS;
        int gq = q0 + q; if (gq >= NQ) gq = NQ - 1;
        float x = logits[(size_t)gq * NCLS + lab];
        float p = 1.0f / (1.0f + __expf(-x));
        float pos = 0.25f * (1.0f - p) * (1.0f - p) * (-__logf(p + 1e-8f));
        float neg = 0.75f * p * p * (-__logf(1.0f - p + 1e-8f));
        ccT[lab][q] = 2.0f * (pos - neg) + 2.0f;
    }

    // --- per-query data: wave-uniform loads, kept in 36 registers ---
    float qx1[QTILE], qy1[QTILE], qx2[QTILE], qy2[QTILE];
    float qcx[QTILE], qcy[QTILE], qw[QTILE], qh[QTILE], qa[QTILE];
#pragma unroll
    for (int q = 0; q < QTILE; ++q) {
        int gq = q0 + q; if (gq >= NQ) gq = NQ - 1;
        float4 pb = reinterpret_cast<const float4*>(pboxes)[gq];
        qcx[q] = pb.x; qcy[q] = pb.y; qw[q] = pb.z; qh[q] = pb.w;
        qx1[q] = pb.x - 0.5f * pb.z;  qy1[q] = pb.y - 0.5f * pb.w;
        qx2[q] = pb.x + 0.5f * pb.z;  qy2[q] = pb.y + 0.5f * pb.w;
        qa[q]  = (qx2[q] - qx1[q]) * (qy2[q] - qy1[q]);  // area from xyxy, like ref
    }
    __syncthreads();

    const float4* tb4  = reinterpret_cast<const float4*>(tboxes);
    const int4*   lb4  = reinterpret_cast<const int4*>(tlabels);
    const float4* ccv  = reinterpret_cast<const float4*>(ccT);
    const bool qfull = (q0 + QTILE <= NQ);

    const int nquad = T >> 2;   // T divisible by 4 (1600)
    for (int quad = tid; quad < nquad; quad += NTHR) {
        const int t0 = quad << 2;
        float4 b[4];
        b[0] = tb4[t0]; b[1] = tb4[t0 + 1]; b[2] = tb4[t0 + 2]; b[3] = tb4[t0 + 3];
        int4 L = lb4[quad];
        float4 cls[4];   // cls[j] = table row for label of t0+j -> 4 q values
        cls[0] = ccv[L.x]; cls[1] = ccv[L.y]; cls[2] = ccv[L.z]; cls[3] = ccv[L.w];

        float bcx[4], bcy[4], bw[4], bh[4], ba[4];
#pragma unroll
        for (int j = 0; j < 4; ++j) {
            bcx[j] = 0.5f * (b[j].x + b[j].z);
            bcy[j] = 0.5f * (b[j].y + b[j].w);
            bw[j]  = b[j].z - b[j].x;
            bh[j]  = b[j].w - b[j].y;
            ba[j]  = bw[j] * bh[j];
        }

#pragma unroll
        for (int q = 0; q < QTILE; ++q) {
            float rr[4];
#pragma unroll
            for (int j = 0; j < 4; ++j) {
                float l1 = fabsf(qcx[q] - bcx[j]) + fabsf(qcy[q] - bcy[j])
                         + fabsf(qw[q]  - bw[j])  + fabsf(qh[q]  - bh[j]);

                float ix1 = fmaxf(qx1[q], b[j].x), iy1 = fmaxf(qy1[q], b[j].y);
                float ix2 = fminf(qx2[q], b[j].z), iy2 = fminf(qy2[q], b[j].w);
                float iw = fmaxf(ix2 - ix1, 0.0f), ih = fmaxf(iy2 - iy1, 0.0f);
                float inter = iw * ih;
                float uni = qa[q] + ba[j] - inter;

                float cx1 = fminf(qx1[q], b[j].x), cy1 = fminf(qy1[q], b[j].y);
                float cx2 = fmaxf(qx2[q], b[j].z), cy2 = fmaxf(qy2[q], b[j].w);
                float ca = (cx2 - cx1) * (cy2 - cy1);   // >0 always (boxes have extent)

                float clsq = (q == 0) ? cls[j].x : (q == 1) ? cls[j].y
                           : (q == 2) ? cls[j].z : cls[j].w;

                // cost = 5*l1 + (2*cls+2) - 2*inter/uni - 2*uni/ca
                float base = fmaf(5.0f, l1, clsq);
                float ru = __builtin_amdgcn_rcpf(uni);   // ~1 ulp
                float rc = __builtin_amdgcn_rcpf(ca);
                rr[j] = fmaf(-2.0f * inter, ru, fmaf(-2.0f * uni, rc, base));
            }
            if (qfull || (q0 + q < NQ)) {
                float4 r; r.x = rr[0]; r.y = rr[1]; r.z = rr[2]; r.w = rr[3];
                reinterpret_cast<float4*>(out + (size_t)(q0 + q) * T)[quad] = r;
            }
        }
    }
}

extern "C" void kernel_launch(void* const* d_in, const int* in_sizes, int n_in,
                              void* d_out, int out_size, void* d_ws, size_t ws_size,
                              hipStream_t stream) {
    const float* logits  = (const float*)d_in[0];  // [16,900,80]
    const float* pboxes  = (const float*)d_in[1];  // [16,900,4]
    const float* tboxes  = (const float*)d_in[2];  // [1600,4]
    const int*   tlabels = (const int*)d_in[3];    // [1600]
    float* out = (float*)d_out;

    const int NQ = in_sizes[1] / 4;   // 14400
    const int T  = in_sizes[2] / 4;   // 1600

    const int nblocks = (NQ + QTILE - 1) / QTILE;  // 3600
    matcher_cost_kernel<<<nblocks, NTHR, 0, stream>>>(logits, pboxes, tboxes,
                                                      tlabels, out, NQ, T);
}

// Round 3
// 34.090 us; speedup vs baseline: 1.1494x; 1.1177x over previous
//
#include <hip/hip_runtime.h>
#include <math.h>

// Fused DETR HungarianMatcher cost matrix:
//   C[nq, t] = 5*L1(pred_cxcywh, tgt_cxcywh) + 2*focal_cls(prob[nq, lab[t]])
//              - 2*GIoU(pred_xyxy, tgt_xyxy)
// NQ = 14400, T = 1600, C = 80. Output f32 [NQ, T].
//
// Round-3 cuts vs round-2 (38.1us):
//  - enclosing box via max+min=a+b identity: cw = qw+bw-iwd (no extra min/max,
//    provably positive -> clamp-free)
//  - single rcp: -2*inter/uni - 2*uni/ca = -2*(inter*ca + uni^2)/(uni*ca)
//  - 32-bit store indexing off a hoisted float4 row base (no 64-bit adds/store)
//  - trimmed live registers (target <=128 VGPR -> 4 waves/SIMD)

#define NCLS  80
#define QTILE 4
#define NTHR  256

__global__ __launch_bounds__(NTHR)
void matcher_cost_kernel(const float* __restrict__ logits,   // [NQ, 80]
                         const float* __restrict__ pboxes,   // [NQ, 4] cxcywh
                         const float* __restrict__ tboxes,   // [T, 4] xyxy
                         const int*   __restrict__ tlabels,  // [T]
                         float* __restrict__ out,            // [NQ, T]
                         int NQ, int T)
{
    __shared__ float ccT[NCLS][QTILE];   // [label][q] : 2*cls + 2 (W_CLASS & GIoU const folded)

    const int tid = threadIdx.x;
    const int q0  = blockIdx.x * QTILE;

    // --- focal class-cost table, transposed (320 entries) ---
    for (int i = tid; i < NCLS * QTILE; i += NTHR) {
        int q = i / NCLS, lab = i - q * NCLS;
        int gq = q0 + q; if (gq >= NQ) gq = NQ - 1;
        float x = logits[(size_t)gq * NCLS + lab];
        float p = 1.0f / (1.0f + __expf(-x));
        float pos = 0.25f * (1.0f - p) * (1.0f - p) * (-__logf(p + 1e-8f));
        float neg = 0.75f * p * p * (-__logf(1.0f - p + 1e-8f));
        ccT[lab][q] = 2.0f * (pos - neg) + 2.0f;
    }

    // --- per-query data in registers (wave-uniform loads) ---
    float qx1[QTILE], qy1[QTILE], qx2[QTILE], qy2[QTILE];
    float qcx[QTILE], qcy[QTILE], qw[QTILE], qh[QTILE], qa[QTILE];
#pragma unroll
    for (int q = 0; q < QTILE; ++q) {
        int gq = q0 + q; if (gq >= NQ) gq = NQ - 1;
        float4 pb = reinterpret_cast<const float4*>(pboxes)[gq];
        qcx[q] = pb.x; qcy[q] = pb.y; qw[q] = pb.z; qh[q] = pb.w;
        qx1[q] = pb.x - 0.5f * pb.z;  qy1[q] = pb.y - 0.5f * pb.w;
        qx2[q] = pb.x + 0.5f * pb.z;  qy2[q] = pb.y + 0.5f * pb.w;
        qa[q]  = (qx2[q] - qx1[q]) * (qy2[q] - qy1[q]);  // area from xyxy, like ref
    }
    __syncthreads();

    const float4* tb4 = reinterpret_cast<const float4*>(tboxes);
    const int4*   lb4 = reinterpret_cast<const int4*>(tlabels);
    const float4* ccv = reinterpret_cast<const float4*>(ccT);

    const int nquad = T >> 2;                       // 400
    float4* obase = reinterpret_cast<float4*>(out) + (size_t)q0 * nquad;
    const bool qfull = (q0 + QTILE <= NQ);

    for (int quad = tid; quad < nquad; quad += NTHR) {
        const int t0 = quad << 2;
        float4 b0 = tb4[t0], b1 = tb4[t0 + 1], b2 = tb4[t0 + 2], b3 = tb4[t0 + 3];
        int4 L = lb4[quad];
        float4 cls0 = ccv[L.x], cls1 = ccv[L.y], cls2 = ccv[L.z], cls3 = ccv[L.w];

        float bx1[4] = {b0.x, b1.x, b2.x, b3.x};
        float by1[4] = {b0.y, b1.y, b2.y, b3.y};
        float bx2[4] = {b0.z, b1.z, b2.z, b3.z};
        float by2[4] = {b0.w, b1.w, b2.w, b3.w};
        float bcx[4], bcy[4], bw[4], bh[4], ba[4];
#pragma unroll
        for (int j = 0; j < 4; ++j) {
            bcx[j] = 0.5f * (bx1[j] + bx2[j]);
            bcy[j] = 0.5f * (by1[j] + by2[j]);
            bw[j]  = bx2[j] - bx1[j];
            bh[j]  = by2[j] - by1[j];
            ba[j]  = bw[j] * bh[j];
        }

#pragma unroll
        for (int q = 0; q < QTILE; ++q) {
            float rr[4];
#pragma unroll
            for (int j = 0; j < 4; ++j) {
                float l1 = (fabsf(qcx[q] - bcx[j]) + fabsf(qcy[q] - bcy[j]))
                         + (fabsf(qw[q]  - bw[j])  + fabsf(qh[q]  - bh[j]));

                float ix1 = fmaxf(qx1[q], bx1[j]), iy1 = fmaxf(qy1[q], by1[j]);
                float ix2 = fminf(qx2[q], bx2[j]), iy2 = fminf(qy2[q], by2[j]);
                float iwd = ix2 - ix1,              ihd = iy2 - iy1;
                float inter = fmaxf(iwd, 0.0f) * fmaxf(ihd, 0.0f);
                float uni = (qa[q] + ba[j]) - inter;
                // enclosing box: max(a,b)+min(a,b)=a+b  =>  cw=qw+bw-iwd (>0 always)
                float cw = (qw[q] + bw[j]) - iwd;
                float ch = (qh[q] + bh[j]) - ihd;
                float ca = cw * ch;

                float clsq = (q == 0) ? cls0.x : (q == 1) ? cls0.y
                           : (q == 2) ? cls0.z : cls0.w;
                if (j == 1) clsq = (q == 0) ? cls1.x : (q == 1) ? cls1.y
                                 : (q == 2) ? cls1.z : cls1.w;
                if (j == 2) clsq = (q == 0) ? cls2.x : (q == 1) ? cls2.y
                                 : (q == 2) ? cls2.z : cls2.w;
                if (j == 3) clsq = (q == 0) ? cls3.x : (q == 1) ? cls3.y
                                 : (q == 2) ? cls3.z : cls3.w;

                // cost = 5*l1 + (2*cls+2) - 2*(inter*ca + uni^2)/(uni*ca)
                float base  = fmaf(5.0f, l1, clsq);
                float denom = uni * ca;
                float r     = __builtin_amdgcn_rcpf(denom);   // ~1 ulp
                float numer = fmaf(uni, uni, inter * ca);
                rr[j] = fmaf(-2.0f * numer, r, base);
            }
            if (qfull || (q0 + q < NQ)) {
                float4 v; v.x = rr[0]; v.y = rr[1]; v.z = rr[2]; v.w = rr[3];
                obase[q * nquad + quad] = v;   // 32-bit index, saddr+voffset
            }
        }
    }
}

extern "C" void kernel_launch(void* const* d_in, const int* in_sizes, int n_in,
                              void* d_out, int out_size, void* d_ws, size_t ws_size,
                              hipStream_t stream) {
    const float* logits  = (const float*)d_in[0];  // [16,900,80]
    const float* pboxes  = (const float*)d_in[1];  // [16,900,4]
    const float* tboxes  = (const float*)d_in[2];  // [1600,4]
    const int*   tlabels = (const int*)d_in[3];    // [1600]
    float* out = (float*)d_out;

    const int NQ = in_sizes[1] / 4;   // 14400
    const int T  = in_sizes[2] / 4;   // 1600

    const int nblocks = (NQ + QTILE - 1) / QTILE;  // 3600
    matcher_cost_kernel<<<nblocks, NTHR, 0, stream>>>(logits, pboxes, tboxes,
                                                      tlabels, out, NQ, T);
}